// Round 12
// baseline (1032.021 us; speedup 1.0000x reference)
//
#include <hip/hip_runtime.h>
#include <hip/hip_bf16.h>

// MANO forward: B=16384, V=778, J=16, NB=10, NPCA=6.
// R13: R12 post-mortem — traffic (537MB) is far below the demonstrated
// ~1.9TB/s combined L2<->L3 rate, so the kernel is latency/VALU-bound.
// Occupancy (21.6%) is GRID-capped: 512 blocks = exactly 2 blocks/CU =
// 2 waves/SIMD; LDS (51.7KB -> 3 blocks/CU) and VGPR (128 <= 170) both
// allow 3. Fix: split the super-tile pair range across 2 blocks
// (grid 1024; half 0 -> pairs 0..12, half 1 -> 13..24). Table is
// col-partitioned by sp so total FETCH is unchanged; stage1 runs per
// half (cheap); joints written by half 0 only. fp32/fallback paths split
// the vertex-iter range. WRITE mechanics: 3 failed predictions -> stop
// betting on it; unchanged epilogue.

typedef __hip_bfloat16 bf16;
typedef unsigned short u16;
typedef unsigned int u32;
typedef __attribute__((ext_vector_type(8))) short short8;
typedef __attribute__((ext_vector_type(4))) float f32x4;

#define BATCH 16384
#define NVERT 778
#define NJOINT 16
#define NSHAPE 10
#define NPCA 6
#define NPF 135                 // (J-1)*9
#define PD_COLS (NVERT * 3)     // 2334
#define VERT_ELEMS ((size_t)BATCH * NVERT * 3)
#define BB 32                   // batches per block
#define NBLK (BATCH / BB)       // 512 batch-groups
#define NSPL 2                  // sp-range split factor (grid = NBLK*NSPL)
#define NSUPER 49               // 49 col super-tiles of 48 (16 vertices)
#define NPAIR 25                // super-tile pairs (last is a singleton)
#define NCTILE 147              // 16-col MFMA tiles (2352 cols, padded)
#define NCHUNK 34               // fp32 vector path chunks
#define PDT_CHUNKS 36
#define PDT_ELEMS (PDT_CHUNKS * PD_COLS * 4)   // fp32 table: 336,096 f32
#define MT_ELEMS (NCTILE * 5 * 64 * 8)         // mfma table: 376,320 bf16
#define PDT_BYTE_OFF 4096
#define TRELP 196               // padded f32 per batch row (4 mod 32 banks)

__device__ __forceinline__ float b2f(bf16 x) { return __bfloat162float(x); }
__device__ __forceinline__ bf16  f2b(float x) { return __float2bfloat16(x); }

// PARENTS = [-1,0,1,2,0,4,5,0,7,8,0,10,11,0,13,14]
__device__ __forceinline__ int parent_of(int j) {
    return (j == 0) ? -1 : (((j - 1) % 3 == 0) ? 0 : j - 1);
}

template <typename T> __device__ __forceinline__ float ldv(const void* p, size_t i);
template <> __device__ __forceinline__ float ldv<float>(const void* p, size_t i) {
    return ((const float*)p)[i];
}
template <> __device__ __forceinline__ float ldv<bf16>(const void* p, size_t i) {
    return b2f(((const bf16*)p)[i]);
}

template <typename T> __device__ __forceinline__ void stv(void* p, size_t i, float v);
template <> __device__ __forceinline__ void stv<float>(void* p, size_t i, float v) {
    ((float*)p)[i] = v;
}
template <> __device__ __forceinline__ void stv<bf16>(void* p, size_t i, float v) {
    ((bf16*)p)[i] = f2b(v);
}

__device__ __forceinline__ u16 bf_bits(float x) {
    union { bf16 h; u16 u; } cvt;
    cvt.h = f2b(x);
    return cvt.u;
}
__device__ __forceinline__ float bflo(u32 u) {
    union { u32 i; float f; } t; t.i = u << 16; return t.f;
}
__device__ __forceinline__ float bfhi(u32 u) {
    union { u32 i; float f; } t; t.i = u & 0xffff0000u; return t.f;
}

// ---------------------------------------------------------------------------
// Kernel 0: dtype detector. flag=1 -> fp32.
// ---------------------------------------------------------------------------
__global__ void detect_dtype(const u16* __restrict__ betas_u, int* __restrict__ flag) {
    __shared__ int s_cnt[256];
    int tid = threadIdx.x;
    int cnt = 0;
    for (int i = tid; i < BATCH * NSHAPE; i += 256) {
        int e = (betas_u[i] >> 7) & 0xFF;
        cnt += (e >= 134) ? 1 : 0;
    }
    s_cnt[tid] = cnt;
    __syncthreads();
    for (int s = 128; s > 0; s >>= 1) {
        if (tid < s) s_cnt[tid] += s_cnt[tid + s];
        __syncthreads();
    }
    if (tid == 0) *flag = (s_cnt[0] > 1000) ? 1 : 0;
}

// ---------------------------------------------------------------------------
// Kernel A: fold J_regressor into v_template and shapedirs.
// ---------------------------------------------------------------------------
template <typename T>
__device__ void precompute_body(const void* Jreg, const void* v_template,
                                const void* shapedirs, float* jt, float* jsd) {
    int idx = blockIdx.x * blockDim.x + threadIdx.x;
    if (idx >= 48 + 480) return;
    if (idx < 48) {
        int j = idx / 3, k = idx % 3;
        float acc = 0.f;
        for (int v = 0; v < NVERT; ++v)
            acc += ldv<T>(Jreg, j * NVERT + v) * ldv<T>(v_template, v * 3 + k);
        jt[idx] = acc;
    } else {
        int o = idx - 48;
        int jk = o / NSHAPE, l = o % NSHAPE;
        int j = jk / 3, k = jk % 3;
        float acc = 0.f;
        for (int v = 0; v < NVERT; ++v)
            acc += ldv<T>(Jreg, j * NVERT + v) * ldv<T>(shapedirs, (v * 3 + k) * NSHAPE + l);
        jsd[o] = acc;
    }
}

__global__ void precompute_kernel(const void* Jreg, const void* v_template,
                                  const void* shapedirs, const int* __restrict__ flag,
                                  float* jt, float* jsd) {
    if (*flag) precompute_body<float>(Jreg, v_template, shapedirs, jt, jsd);
    else       precompute_body<bf16 >(Jreg, v_template, shapedirs, jt, jsd);
}

// ---------------------------------------------------------------------------
// Kernel A2: table builder.
// fp32 mode: transposed layout pdT[c][r][4] (float) for the vector path.
// bf16 mode: MFMA B-fragment layout. For tile t (16 cols), K-step ks (K=32),
// lane l, elem i: element = Bsrc[k = ks*32 + (l>>4)*8 + i][col = t*16+(l&15)]
// where Bsrc rows: 0..134 posedirs, 135..144 shapedirsT, 145 v_template.
// ---------------------------------------------------------------------------
__device__ void transpose_f32(const float* pd, float* pdT) {
    int idx = blockIdx.x * blockDim.x + threadIdx.x;
    if (idx >= PDT_ELEMS) return;
    int j = idx & 3;
    int rc = idx >> 2;
    int r = rc % PD_COLS;
    int c = rc / PD_COLS;
    int p = c * 4 + j;
    pdT[idx] = (p < NPF) ? pd[(size_t)p * PD_COLS + r] : 0.f;
}

__device__ void transpose_mfma(const u16* pdu, const u16* sdu, const u16* vtu,
                               u16* out) {
    int idx = blockIdx.x * blockDim.x + threadIdx.x;
    if (idx >= MT_ELEMS) return;
    int i  = idx & 7;
    int l  = (idx >> 3) & 63;
    int u  = idx >> 9;             // t*5 + ks
    int ks = u % 5, t = u / 5;
    int k   = ks * 32 + ((l >> 4) << 3) + i;
    int col = t * 16 + (l & 15);
    u16 bits = 0;
    if (col < PD_COLS) {
        if (k < NPF)                     bits = pdu[(size_t)k * PD_COLS + col];
        else if (k < NPF + NSHAPE)       bits = sdu[(size_t)col * NSHAPE + (k - NPF)];
        else if (k == NPF + NSHAPE)      bits = vtu[col];
    }
    out[idx] = bits;
}

__global__ void transpose_kernel(const void* pd, const void* sd, const void* vt,
                                 const int* __restrict__ flag, void* pdT) {
    if (*flag) transpose_f32((const float*)pd, (float*)pdT);
    else       transpose_mfma((const u16*)pd, (const u16*)sd, (const u16*)vt,
                              (u16*)pdT);
}

// ---------------------------------------------------------------------------
// Kernel B shared memory.
// ---------------------------------------------------------------------------
struct __align__(16) SmemB {
    union {
        float pff[16][144];        // fp32 vector path pose features
        u16   pfA[32][168];        // bf16 MFMA A rows: pf|beta|1|0 pad
    } pf;                          // 10752 B
    float trel[BB * TRELP];        // tm then rel, stride 196 (2-way banks) 25088 B
    union {
        float joints[BB][NJOINT][3];   // stage-1 only               6144 B
        float ldsC[4][16][52];         // bf16 per-wave C / out pack 13312 B
        float ob[4][4][192];           // fp32 vector output staging 12288 B
    } c;                           // 13312 B
    float beta[BB][NSHAPE];        // 1280 B
    float transl[BB][3];           //  384 B
    float hp[BB][NPCA];            //  768 B
};                                 // ~51.6 KB

// ---------------------------------------------------------------------------
// Stage 1: 16 batches (b0s..b0s+15) -> LDS rows ro..ro+15. 4 internal syncs.
// wjoints: write posed joints to global (only one split-half does this).
// ---------------------------------------------------------------------------
template <typename T>
__device__ void stage1(const void* betas, const void* orient,
                       const void* hand_pose, const void* transl,
                       const void* hc, const void* pose_mean,
                       const float* __restrict__ jt, const float* __restrict__ jsd,
                       int b0s, int ro, bool wjoints, void* out_base, SmemB& s) {
    const int tid = threadIdx.x;

    // stage 0: per-batch small inputs
    if (tid < 160) {
        int q = tid / NSHAPE, l = tid % NSHAPE;
        s.beta[ro + q][l] = ldv<T>(betas, (size_t)(b0s + q) * NSHAPE + l);
    } else if (tid < 208) {
        int o = tid - 160;
        int q = o / 3, k = o % 3;
        s.transl[ro + q][k] = ldv<T>(transl, (size_t)(b0s + q) * 3 + k);
    } else {
        int o = tid - 208;
        #pragma unroll
        for (int rep = 0; rep < 2; ++rep) {
            int oo = o + rep * 48;
            int q = oo / NPCA, c = oo % NPCA;
            s.hp[ro + q][c] = ldv<T>(hand_pose, (size_t)(b0s + q) * NPCA + c);
        }
    }
    __syncthreads();

    const int bb = tid >> 4;       // 0..15
    const int j  = tid & 15;
    const int rb = ro + bb;
    float R[9];
    float jx[3];
    {
        float p0, p1, p2;
        if (j == 0) {
            const int b = b0s + bb;
            p0 = ldv<T>(orient, (size_t)b * 3 + 0) + ldv<T>(pose_mean, 0);
            p1 = ldv<T>(orient, (size_t)b * 3 + 1) + ldv<T>(pose_mean, 1);
            p2 = ldv<T>(orient, (size_t)b * 3 + 2) + ldv<T>(pose_mean, 2);
        } else {
            int base = 3 * (j - 1);
            p0 = ldv<T>(pose_mean, 3 * j + 0);
            p1 = ldv<T>(pose_mean, 3 * j + 1);
            p2 = ldv<T>(pose_mean, 3 * j + 2);
            #pragma unroll
            for (int c = 0; c < NPCA; ++c) {
                float hpv = s.hp[rb][c];
                p0 += hpv * ldv<T>(hc, c * 45 + base + 0);
                p1 += hpv * ldv<T>(hc, c * 45 + base + 1);
                p2 += hpv * ldv<T>(hc, c * 45 + base + 2);
            }
        }

        float r0 = p0 + 1e-8f, r1 = p1 + 1e-8f, r2 = p2 + 1e-8f;
        float angle = sqrtf(r0 * r0 + r1 * r1 + r2 * r2);
        float inv = 1.f / angle;
        float ax = p0 * inv, ay = p1 * inv, az = p2 * inv;
        float sn = sinf(angle);
        float cc1 = 1.f - cosf(angle);
        R[0] = 1.f + cc1 * (-az * az - ay * ay);
        R[1] = -sn * az + cc1 * ax * ay;
        R[2] =  sn * ay + cc1 * ax * az;
        R[3] =  sn * az + cc1 * ax * ay;
        R[4] = 1.f + cc1 * (-az * az - ax * ax);
        R[5] = -sn * ax + cc1 * ay * az;
        R[6] = -sn * ay + cc1 * ax * az;
        R[7] =  sn * ax + cc1 * ay * az;
        R[8] = 1.f + cc1 * (-ax * ax - ay * ay);

        #pragma unroll
        for (int k = 0; k < 3; ++k) {
            float acc = jt[j * 3 + k];
            #pragma unroll
            for (int l = 0; l < NSHAPE; ++l)
                acc += jsd[(j * 3 + k) * NSHAPE + l] * s.beta[rb][l];
            jx[k] = acc;
            s.c.joints[rb][j][k] = acc;
        }
    }
    __syncthreads();

    // local transform [R | joint - parent_joint] into trel
    {
        int par = parent_of(j);
        float* tm = &s.trel[(size_t)rb * TRELP + j * 12];
        #pragma unroll
        for (int m = 0; m < 3; ++m) {
            float t = jx[m] - (j > 0 ? s.c.joints[rb][par][m] : 0.f);
            tm[m * 4 + 0] = R[m * 3 + 0];
            tm[m * 4 + 1] = R[m * 3 + 1];
            tm[m * 4 + 2] = R[m * 3 + 2];
            tm[m * 4 + 3] = t;
        }
    }
    __syncthreads();

    // chain walk
    float G[12];
    {
        int stack[3];
        int depth = 0;
        int i = j;
        while (i != 0 && depth < 3) { stack[depth++] = i; i = parent_of(i); }
        const float* base = &s.trel[(size_t)rb * TRELP];
        #pragma unroll
        for (int t = 0; t < 12; ++t) G[t] = base[t];
        for (int d = depth - 1; d >= 0; --d) {
            const float* Tc = base + stack[d] * 12;
            float Gn[12];
            #pragma unroll
            for (int m = 0; m < 3; ++m) {
                #pragma unroll
                for (int n = 0; n < 4; ++n) {
                    float acc = G[m * 4 + 0] * Tc[0 * 4 + n] +
                                G[m * 4 + 1] * Tc[1 * 4 + n] +
                                G[m * 4 + 2] * Tc[2 * 4 + n];
                    if (n == 3) acc += G[m * 4 + 3];
                    Gn[m * 4 + n] = acc;
                }
            }
            #pragma unroll
            for (int t = 0; t < 12; ++t) G[t] = Gn[t];
        }
    }
    __syncthreads();    // all chain reads done; now overwrite with rel

    {
        // posed joints out (+ transl) — only one split-half writes
        if (wjoints) {
            size_t jo = VERT_ELEMS + ((size_t)(b0s + bb) * NJOINT + j) * 3;
            stv<T>(out_base, jo + 0, G[0 * 4 + 3] + s.transl[rb][0]);
            stv<T>(out_base, jo + 1, G[1 * 4 + 3] + s.transl[rb][1]);
            stv<T>(out_base, jo + 2, G[2 * 4 + 3] + s.transl[rb][2]);
        }

        float* rl = &s.trel[(size_t)rb * TRELP + j * 12];
        #pragma unroll
        for (int m = 0; m < 3; ++m) {
            float rbv = G[m * 4 + 3] -
                        (G[m * 4 + 0] * jx[0] + G[m * 4 + 1] * jx[1] + G[m * 4 + 2] * jx[2]);
            rl[m * 4 + 0] = G[m * 4 + 0];
            rl[m * 4 + 1] = G[m * 4 + 1];
            rl[m * 4 + 2] = G[m * 4 + 2];
            rl[m * 4 + 3] = rbv;
        }

        if constexpr (sizeof(T) == 2) {
            u16* pa = &s.pf.pfA[rb][0];
            if (j > 0) {
                u16* po = pa + (j - 1) * 9;
                po[0] = bf_bits(R[0] - 1.f); po[1] = bf_bits(R[1]);       po[2] = bf_bits(R[2]);
                po[3] = bf_bits(R[3]);       po[4] = bf_bits(R[4] - 1.f); po[5] = bf_bits(R[5]);
                po[6] = bf_bits(R[6]);       po[7] = bf_bits(R[7]);       po[8] = bf_bits(R[8] - 1.f);
            } else {
                #pragma unroll
                for (int l2 = 0; l2 < NSHAPE; ++l2)
                    pa[NPF + l2] = bf_bits(s.beta[rb][l2]);
                pa[NPF + NSHAPE] = 0x3F80;  // 1.0 bf16
                #pragma unroll
                for (int z = NPF + NSHAPE + 1; z < 168; ++z) pa[z] = 0;
            }
        } else {
            float* pa = s.pf.pff[bb];
            if (j > 0) {
                float* po = pa + (j - 1) * 9;
                po[0] = R[0] - 1.f; po[1] = R[1];       po[2] = R[2];
                po[3] = R[3];       po[4] = R[4] - 1.f; po[5] = R[5];
                po[6] = R[6];       po[7] = R[7];       po[8] = R[8] - 1.f;
            } else {
                #pragma unroll
                for (int z = NPF; z < 144; ++z) pa[z] = 0.f;
            }
        }
    }
    __syncthreads();
}

// ---------------------------------------------------------------------------
// bf16 MFMA stage 2 helpers.
// lbs_calc: LBS epilogue for one (half h, super-tile sp); result packed into
// out6 (6 u32 = 12 bf16 = 4 vertices x 3 coords for this lane's slice).
// ---------------------------------------------------------------------------
__device__ __forceinline__ void lbs_calc(const void* lbsw, int h, int sp,
                                         SmemB& s, float (*ldsC)[52], int l,
                                         u32 out6[6]) {
    const int lb = l & 15, vg = l >> 4;
    asm volatile("s_waitcnt lgkmcnt(0)" ::: "memory");
    __builtin_amdgcn_sched_barrier(0);

    float a4[4][3];
    #pragma unroll
    for (int vv = 0; vv < 4; ++vv)
        #pragma unroll
        for (int cc = 0; cc < 3; ++cc)
            a4[vv][cc] = ldsC[lb][(vg * 4 + vv) * 3 + cc];

    uint4 wr[4][2];
    #pragma unroll
    for (int vv = 0; vv < 4; ++vv) {
        int v = sp * 16 + vg * 4 + vv;
        if (v > NVERT - 1) v = NVERT - 1;
        const uint4* wp = (const uint4*)((const u16*)lbsw + (size_t)v * NJOINT);
        wr[vv][0] = wp[0];
        wr[vv][1] = wp[1];
    }

    const float* relb = &s.trel[(size_t)(h * 16 + lb) * TRELP];
    float Tm[4][12];
    #pragma unroll
    for (int vv = 0; vv < 4; ++vv)
        #pragma unroll
        for (int q = 0; q < 12; ++q) Tm[vv][q] = 0.f;

    #pragma unroll
    for (int jj = 0; jj < NJOINT; ++jj) {
        const float4 r0 = *(const float4*)(relb + jj * 12 + 0);
        const float4 r1 = *(const float4*)(relb + jj * 12 + 4);
        const float4 r2 = *(const float4*)(relb + jj * 12 + 8);
        #pragma unroll
        for (int vv = 0; vv < 4; ++vv) {
            const uint4 wu = wr[vv][(jj >> 3) & 1];
            const int wc = (jj >> 1) & 3;
            const u32 ww = (wc == 0) ? wu.x : (wc == 1) ? wu.y : (wc == 2) ? wu.z : wu.w;
            const float wj = (jj & 1) ? bfhi(ww) : bflo(ww);
            Tm[vv][0] += wj * r0.x; Tm[vv][1]  += wj * r0.y; Tm[vv][2]  += wj * r0.z; Tm[vv][3]  += wj * r0.w;
            Tm[vv][4] += wj * r1.x; Tm[vv][5]  += wj * r1.y; Tm[vv][6]  += wj * r1.z; Tm[vv][7]  += wj * r1.w;
            Tm[vv][8] += wj * r2.x; Tm[vv][9]  += wj * r2.y; Tm[vv][10] += wj * r2.z; Tm[vv][11] += wj * r2.w;
        }
    }

    const float t0 = s.transl[h * 16 + lb][0];
    const float t1 = s.transl[h * 16 + lb][1];
    const float t2 = s.transl[h * 16 + lb][2];
    float o[4][3];
    #pragma unroll
    for (int vv = 0; vv < 4; ++vv) {
        o[vv][0] = Tm[vv][0] * a4[vv][0] + Tm[vv][1] * a4[vv][1] + Tm[vv][2]  * a4[vv][2] + Tm[vv][3]  + t0;
        o[vv][1] = Tm[vv][4] * a4[vv][0] + Tm[vv][5] * a4[vv][1] + Tm[vv][6]  * a4[vv][2] + Tm[vv][7]  + t1;
        o[vv][2] = Tm[vv][8] * a4[vv][0] + Tm[vv][9] * a4[vv][1] + Tm[vv][10] * a4[vv][2] + Tm[vv][11] + t2;
    }

    out6[0] = (u32)bf_bits(o[0][0]) | ((u32)bf_bits(o[0][1]) << 16);
    out6[1] = (u32)bf_bits(o[0][2]) | ((u32)bf_bits(o[1][0]) << 16);
    out6[2] = (u32)bf_bits(o[1][1]) | ((u32)bf_bits(o[1][2]) << 16);
    out6[3] = (u32)bf_bits(o[2][0]) | ((u32)bf_bits(o[2][1]) << 16);
    out6[4] = (u32)bf_bits(o[2][2]) | ((u32)bf_bits(o[3][0]) << 16);
    out6[5] = (u32)bf_bits(o[3][1]) | ((u32)bf_bits(o[3][2]) << 16);
}

// compute one super-tile sp for both halves; results in rh0/rh1.
__device__ __forceinline__ void super_tile(const u16* __restrict__ pdTm,
                                           const void* lbsw, int sp,
                                           const short8* afr0, const short8* afr1,
                                           SmemB& s, float (*ldsC)[52],
                                           int l, int lq, int lb,
                                           u32 rh0[6], u32 rh1[6]) {
    f32x4 acc1[3];
    #pragma unroll
    for (int tt = 0; tt < 3; ++tt) {
        const int t = sp * 3 + tt;
        f32x4 a0 = {0.f, 0.f, 0.f, 0.f};
        f32x4 a1 = {0.f, 0.f, 0.f, 0.f};
        #pragma unroll
        for (int ks = 0; ks < 5; ++ks) {
            const short8 bfr = *(const short8*)(pdTm + (((size_t)t * 5 + ks) * 64 + l) * 8);
            a0 = __builtin_amdgcn_mfma_f32_16x16x32_bf16(afr0[ks], bfr, a0, 0, 0, 0);
            a1 = __builtin_amdgcn_mfma_f32_16x16x32_bf16(afr1[ks], bfr, a1, 0, 0, 0);
        }
        #pragma unroll
        for (int r = 0; r < 4; ++r) ldsC[lq * 4 + r][tt * 16 + lb] = a0[r];
        acc1[tt] = a1;
    }
    lbs_calc(lbsw, 0, sp, s, ldsC, l, rh0);
    #pragma unroll
    for (int tt = 0; tt < 3; ++tt)
        #pragma unroll
        for (int r = 0; r < 4; ++r) ldsC[lq * 4 + r][tt * 16 + lb] = acc1[tt][r];
    lbs_calc(lbsw, 1, sp, s, ldsC, l, rh1);
}

__device__ void mfma_stage2(const u16* __restrict__ pdTm, const void* lbsw,
                            int b0, int p0, int p1, void* out_base, SmemB& s) {
    const int tid = threadIdx.x;
    const int wv = tid >> 6, l = tid & 63;
    const int lb = l & 15, lq = l >> 4;
    const int vg = l >> 4;
    float (*ldsC)[52] = s.c.ldsC[wv];

    for (int p = p0 + wv; p < p1; p += 4) {
        short8 afr0[5], afr1[5];
        #pragma unroll
        for (int ks = 0; ks < 5; ++ks) {
            afr0[ks] = *(const short8*)&s.pf.pfA[lb][ks * 32 + lq * 8];
            afr1[ks] = *(const short8*)&s.pf.pfA[16 + lb][ks * 32 + lq * 8];
        }

        u32 r00[6], r01[6], r10[6], r11[6];
        #pragma unroll
        for (int k = 0; k < 6; ++k) { r10[k] = 0u; r11[k] = 0u; }

        super_tile(pdTm, lbsw, 2 * p, afr0, afr1, s, ldsC, l, lq, lb, r00, r01);
        if (p < NPAIR - 1)   // last pair is a singleton (sp=48)
            super_tile(pdTm, lbsw, 2 * p + 1, afr0, afr1, s, ldsC, l, lq, lb, r10, r11);

        // pack both sps + write: 48 u32 (192 B) per batch row.
        const int nw = (p == NPAIR - 1) ? 15 : 48;   // valid u32 per row
        #pragma unroll
        for (int h = 0; h < 2; ++h) {
            const u32* rA = (h == 0) ? r00 : r01;
            const u32* rB = (h == 0) ? r10 : r11;
            asm volatile("s_waitcnt lgkmcnt(0)" ::: "memory");
            __builtin_amdgcn_sched_barrier(0);
            u32* row = (u32*)&ldsC[lb][0];
            #pragma unroll
            for (int k = 0; k < 6; ++k) {
                row[vg * 6 + k]      = rA[k];
                row[24 + vg * 6 + k] = rB[k];
            }
            asm volatile("s_waitcnt lgkmcnt(0)" ::: "memory");
            __builtin_amdgcn_sched_barrier(0);
            #pragma unroll
            for (int it = 0; it < 12; ++it) {
                const int i = it * 64 + l;
                const int bb2 = i / 48, c2 = i - bb2 * 48;
                if (c2 < nw) {
                    const u32 val = ((const u32*)&ldsC[bb2][0])[c2];
                    *(u32*)((char*)out_base + (size_t)(b0 + h * 16 + bb2) * (NVERT * 3 * 2)
                            + (size_t)p * 192 + (size_t)c2 * 4) = val;
                }
            }
        }
    }
}

// ---------------------------------------------------------------------------
// Vector stage 2 (fp32 TRP = transposed table; generic otherwise).
// Operates on LDS rows 0..15 / batches b0s..b0s+15. iter range [it0, it1).
// ---------------------------------------------------------------------------
template <typename T, bool TRP>
__device__ void vector_stage2(const void* v_template, const void* shapedirs,
                              const void* posedirs, const void* lbsw,
                              const void* __restrict__ pdTv,
                              int b0s, int it0, int it1,
                              void* out_base, SmemB& s) {
    const int tid = threadIdx.x;
    const int wv = tid >> 6;
    const int ln = tid & 63;

    for (int iter = it0; iter < it1; ++iter) {
        const int vbase = iter * 256 + wv * 64;
        if (vbase >= NVERT) break;
        const int nv = (NVERT - vbase < 64) ? (NVERT - vbase) : 64;
        const int v  = vbase + ln;
        const int vc = (v < NVERT) ? v : (NVERT - 1);
        const int v3 = vc * 3;

        float a[16][3];
        {
            const float q0 = ldv<T>(v_template, v3 + 0);
            const float q1 = ldv<T>(v_template, v3 + 1);
            const float q2 = ldv<T>(v_template, v3 + 2);
            #pragma unroll
            for (int q = 0; q < 16; ++q) { a[q][0] = q0; a[q][1] = q1; a[q][2] = q2; }
        }

        #pragma unroll
        for (int l = 0; l < NSHAPE; ++l) {
            const float sd0 = ldv<T>(shapedirs, (size_t)vc * 30 + 0 * NSHAPE + l);
            const float sd1 = ldv<T>(shapedirs, (size_t)vc * 30 + 1 * NSHAPE + l);
            const float sd2 = ldv<T>(shapedirs, (size_t)vc * 30 + 2 * NSHAPE + l);
            #pragma unroll
            for (int q = 0; q < 16; ++q) {
                const float be = s.beta[q][l];
                a[q][0] += be * sd0;
                a[q][1] += be * sd1;
                a[q][2] += be * sd2;
            }
        }

        auto fma_chunk = [&](float4 px, float4 py, float4 pz, int c) {
            #pragma unroll
            for (int q = 0; q < 16; ++q) {
                const float4 f = *(const float4*)&s.pf.pff[q][c * 4];
                a[q][0] += f.x * px.x + f.y * px.y + f.z * px.z + f.w * px.w;
                a[q][1] += f.x * py.x + f.y * py.y + f.z * py.z + f.w * py.w;
                a[q][2] += f.x * pz.x + f.y * pz.y + f.z * pz.z + f.w * pz.w;
            }
        };

        if constexpr (TRP && sizeof(T) == 4) {
            const float4* __restrict__ pdT4 = (const float4*)pdTv;
            float4 ax = pdT4[(size_t)0 * PD_COLS + v3 + 0];
            float4 ay = pdT4[(size_t)0 * PD_COLS + v3 + 1];
            float4 az = pdT4[(size_t)0 * PD_COLS + v3 + 2];
            float4 bx = pdT4[(size_t)1 * PD_COLS + v3 + 0];
            float4 by = pdT4[(size_t)1 * PD_COLS + v3 + 1];
            float4 bz = pdT4[(size_t)1 * PD_COLS + v3 + 2];
            #pragma unroll 1
            for (int c = 0; c < NCHUNK; c += 2) {
                const size_t n2 = (size_t)(c + 2) * PD_COLS + v3;
                const size_t n3 = (size_t)(c + 3) * PD_COLS + v3;
                float4 cx = pdT4[n2 + 0], cy = pdT4[n2 + 1], cz = pdT4[n2 + 2];
                float4 dx = pdT4[n3 + 0], dy = pdT4[n3 + 1], dz = pdT4[n3 + 2];
                fma_chunk(ax, ay, az, c);
                fma_chunk(bx, by, bz, c + 1);
                ax = cx; ay = cy; az = cz;
                bx = dx; by = dy; bz = dz;
            }
        } else {
            #pragma unroll 1
            for (int c = 0; c < NCHUNK; ++c) {
                const int p = c * 4;
                float pdx[4], pdy[4], pdz[4];
                #pragma unroll
                for (int qq = 0; qq < 3; ++qq) {
                    pdx[qq] = ldv<T>(posedirs, (size_t)(p + qq) * PD_COLS + v3 + 0);
                    pdy[qq] = ldv<T>(posedirs, (size_t)(p + qq) * PD_COLS + v3 + 1);
                    pdz[qq] = ldv<T>(posedirs, (size_t)(p + qq) * PD_COLS + v3 + 2);
                }
                if (p + 3 < NPF) {
                    pdx[3] = ldv<T>(posedirs, (size_t)(p + 3) * PD_COLS + v3 + 0);
                    pdy[3] = ldv<T>(posedirs, (size_t)(p + 3) * PD_COLS + v3 + 1);
                    pdz[3] = ldv<T>(posedirs, (size_t)(p + 3) * PD_COLS + v3 + 2);
                } else {
                    pdx[3] = 0.f; pdy[3] = 0.f; pdz[3] = 0.f;
                }
                fma_chunk(make_float4(pdx[0], pdx[1], pdx[2], pdx[3]),
                          make_float4(pdy[0], pdy[1], pdy[2], pdy[3]),
                          make_float4(pdz[0], pdz[1], pdz[2], pdz[3]), c);
            }
        }

        float w[NJOINT];
        if constexpr (sizeof(T) == 4) {
            const float4* wl = (const float4*)((const float*)lbsw + (size_t)vc * NJOINT);
            #pragma unroll
            for (int g = 0; g < 4; ++g) {
                const float4 t = wl[g];
                w[g * 4 + 0] = t.x; w[g * 4 + 1] = t.y;
                w[g * 4 + 2] = t.z; w[g * 4 + 3] = t.w;
            }
        } else {
            const uint4* wl = (const uint4*)((const u16*)lbsw + (size_t)vc * NJOINT);
            const uint4 w0 = wl[0], w1 = wl[1];
            w[0]  = bflo(w0.x); w[1]  = bfhi(w0.x);
            w[2]  = bflo(w0.y); w[3]  = bfhi(w0.y);
            w[4]  = bflo(w0.z); w[5]  = bfhi(w0.z);
            w[6]  = bflo(w0.w); w[7]  = bfhi(w0.w);
            w[8]  = bflo(w1.x); w[9]  = bfhi(w1.x);
            w[10] = bflo(w1.y); w[11] = bfhi(w1.y);
            w[12] = bflo(w1.z); w[13] = bfhi(w1.z);
            w[14] = bflo(w1.w); w[15] = bfhi(w1.w);
        }

        const int n32 = (nv * 3 * (int)sizeof(T)) >> 2;
        #pragma unroll 1
        for (int g = 0; g < 4; ++g) {
            #pragma unroll
            for (int qq = 0; qq < 4; ++qq) {
                const int q = g * 4 + qq;
                float Tm[12];
                #pragma unroll
                for (int t = 0; t < 12; ++t) Tm[t] = 0.f;
                #pragma unroll
                for (int jj = 0; jj < NJOINT; ++jj) {
                    const float* rl = &s.trel[(size_t)q * TRELP + jj * 12];
                    const float4 r0 = *(const float4*)(rl + 0);
                    const float4 r1 = *(const float4*)(rl + 4);
                    const float4 r2 = *(const float4*)(rl + 8);
                    const float wj = w[jj];
                    Tm[0] += wj * r0.x; Tm[1]  += wj * r0.y; Tm[2]  += wj * r0.z; Tm[3]  += wj * r0.w;
                    Tm[4] += wj * r1.x; Tm[5]  += wj * r1.y; Tm[6]  += wj * r1.z; Tm[7]  += wj * r1.w;
                    Tm[8] += wj * r2.x; Tm[9]  += wj * r2.y; Tm[10] += wj * r2.z; Tm[11] += wj * r2.w;
                }
                const float o0 = Tm[0] * a[q][0] + Tm[1] * a[q][1] + Tm[2]  * a[q][2] + Tm[3]  + s.transl[q][0];
                const float o1 = Tm[4] * a[q][0] + Tm[5] * a[q][1] + Tm[6]  * a[q][2] + Tm[7]  + s.transl[q][1];
                const float o2 = Tm[8] * a[q][0] + Tm[9] * a[q][1] + Tm[10] * a[q][2] + Tm[11] + s.transl[q][2];
                if constexpr (sizeof(T) == 4) {
                    float* ob = &s.c.ob[wv][qq][0];
                    ob[ln * 3 + 0] = o0;
                    ob[ln * 3 + 1] = o1;
                    ob[ln * 3 + 2] = o2;
                } else {
                    u16* ob = (u16*)&s.c.ob[wv][qq][0];
                    ob[ln * 3 + 0] = bf_bits(o0);
                    ob[ln * 3 + 1] = bf_bits(o1);
                    ob[ln * 3 + 2] = bf_bits(o2);
                }
            }
            #pragma unroll
            for (int qq = 0; qq < 4; ++qq) {
                const int q = g * 4 + qq;
                const u32* src = (const u32*)&s.c.ob[wv][qq][0];
                u32* dst = (u32*)((char*)out_base +
                                  ((size_t)(b0s + q) * NVERT + vbase) * 3 * sizeof(T));
                #pragma unroll
                for (int k = 0; k < 3; ++k) {
                    const int idx = k * 64 + ln;
                    if (idx < n32) dst[idx] = src[idx];
                }
            }
        }
    }
}

// ---------------------------------------------------------------------------
template <bool TRP>
__global__ __launch_bounds__(256, 2) void mano_fused(
    const void* betas, const void* orient, const void* hand_pose,
    const void* transl, const void* hc, const void* pose_mean,
    const void* v_template, const void* shapedirs, const void* posedirs,
    const void* lbsw, const int* __restrict__ flag,
    const float* __restrict__ jt, const float* __restrict__ jsd,
    const void* __restrict__ pdT,
    void* out_base) {
    __shared__ SmemB s;
    const int bg   = blockIdx.x >> 1;   // batch-group
    const int half = blockIdx.x & 1;    // sp-range half
    const int b0 = bg * BB;
    const bool wj = (half == 0);

    if (*flag) {
        #pragma unroll 1
        for (int rep = 0; rep < 2; ++rep) {
            stage1<float>(betas, orient, hand_pose, transl, hc, pose_mean,
                          jt, jsd, b0 + rep * 16, 0, wj, out_base, s);
            vector_stage2<float, TRP>(v_template, shapedirs, posedirs, lbsw,
                                      pdT, b0 + rep * 16, half * 2, half * 2 + 2,
                                      out_base, s);
            __syncthreads();
        }
    } else {
        if constexpr (TRP) {
            stage1<bf16>(betas, orient, hand_pose, transl, hc, pose_mean,
                         jt, jsd, b0, 0, wj, out_base, s);
            stage1<bf16>(betas, orient, hand_pose, transl, hc, pose_mean,
                         jt, jsd, b0 + 16, 16, wj, out_base, s);
            const int p0 = half ? 13 : 0;
            const int p1 = half ? NPAIR : 13;
            mfma_stage2((const u16*)pdT, lbsw, b0, p0, p1, out_base, s);
        } else {
            #pragma unroll 1
            for (int rep = 0; rep < 2; ++rep) {
                stage1<bf16>(betas, orient, hand_pose, transl, hc, pose_mean,
                             jt, jsd, b0 + rep * 16, 0, wj, out_base, s);
                vector_stage2<bf16, false>(v_template, shapedirs, posedirs, lbsw,
                                           pdT, b0 + rep * 16, half * 2, half * 2 + 2,
                                           out_base, s);
                __syncthreads();
            }
        }
    }
}

// ---------------------------------------------------------------------------
extern "C" void kernel_launch(void* const* d_in, const int* in_sizes, int n_in,
                              void* d_out, int out_size, void* d_ws, size_t ws_size,
                              hipStream_t stream) {
    const void* betas      = d_in[0];
    const void* orient     = d_in[1];
    const void* hand_pose  = d_in[2];
    const void* transl     = d_in[3];
    const void* hc         = d_in[4];
    const void* pose_mean  = d_in[5];
    const void* v_template = d_in[6];
    const void* shapedirs  = d_in[7];
    const void* posedirs   = d_in[8];
    const void* Jreg       = d_in[9];
    const void* lbsw       = d_in[10];
    // d_in[11] (parents) intentionally ignored — tree is hardcoded.

    int*   flag = (int*)d_ws;
    float* jt   = (float*)d_ws + 16;
    float* jsd  = (float*)d_ws + 64;
    void*  pdT  = (void*)((char*)d_ws + PDT_BYTE_OFF);

    // worst case (fp32 table): 36 chunks * 2334 * 4 elems * 4 B
    const bool trp = ws_size >= (size_t)PDT_BYTE_OFF + (size_t)PDT_ELEMS * 4;

    hipLaunchKernelGGL(detect_dtype, dim3(1), dim3(256), 0, stream,
                       (const u16*)betas, flag);
    hipLaunchKernelGGL(precompute_kernel, dim3(3), dim3(192), 0, stream,
                       Jreg, v_template, shapedirs, flag, jt, jsd);
    if (trp) {
        hipLaunchKernelGGL(transpose_kernel, dim3((MT_ELEMS + 255) / 256), dim3(256),
                           0, stream, posedirs, shapedirs, v_template, flag, pdT);
        hipLaunchKernelGGL(mano_fused<true>, dim3(NBLK * NSPL), dim3(256), 0, stream,
                           betas, orient, hand_pose, transl, hc, pose_mean,
                           v_template, shapedirs, posedirs, lbsw, flag, jt, jsd,
                           pdT, d_out);
    } else {
        hipLaunchKernelGGL(mano_fused<false>, dim3(NBLK * NSPL), dim3(256), 0, stream,
                           betas, orient, hand_pose, transl, hc, pose_mean,
                           v_template, shapedirs, posedirs, lbsw, flag, jt, jsd,
                           pdT, d_out);
    }
    (void)in_sizes; (void)n_in; (void)out_size; (void)ws_size;
}

// Round 13
// 963.157 us; speedup vs baseline: 1.0715x; 1.0715x over previous
//
#include <hip/hip_runtime.h>
#include <hip/hip_bf16.h>

// MANO forward: B=16384, V=778, J=16, NB=10, NPCA=6.
// R14: base = R12 (best, 515us). R13 falsified "grid-capped": doubling
// blocks didn't raise residency (20.6%) and duplicated stage1 -> regress.
// The kernel runs ~10x above its ~45us VALU floor -> latency-bound at
// 2 waves/SIMD. Lever: 512-thread blocks (8 waves) sharing ONE stage1 and
// ONE trel/pfA copy per 32 batches; waves split the 25 sp-pairs 8 ways.
// 16 waves/CU = 4/SIMD at unchanged per-block work. LDS 51.7->64.9KB
// (ldsC/ob per-wave staging x2), still 2 blocks/CU. __launch_bounds__(512,4)
// = 128 VGPR budget (the kernel's measured natural footprint).

typedef __hip_bfloat16 bf16;
typedef unsigned short u16;
typedef unsigned int u32;
typedef __attribute__((ext_vector_type(8))) short short8;
typedef __attribute__((ext_vector_type(4))) float f32x4;

#define BATCH 16384
#define NVERT 778
#define NJOINT 16
#define NSHAPE 10
#define NPCA 6
#define NPF 135                 // (J-1)*9
#define PD_COLS (NVERT * 3)     // 2334
#define VERT_ELEMS ((size_t)BATCH * NVERT * 3)
#define BB 32                   // batches per block
#define NBLK (BATCH / BB)       // 512
#define NTHR 512                // threads per block (8 waves)
#define NWV 8
#define NSUPER 49               // 49 col super-tiles of 48 (16 vertices)
#define NPAIR 25                // super-tile pairs (last is a singleton)
#define NCTILE 147              // 16-col MFMA tiles (2352 cols, padded)
#define NCHUNK 34               // fp32 vector path chunks
#define PDT_CHUNKS 36
#define PDT_ELEMS (PDT_CHUNKS * PD_COLS * 4)   // fp32 table: 336,096 f32
#define MT_ELEMS (NCTILE * 5 * 64 * 8)         // mfma table: 376,320 bf16
#define PDT_BYTE_OFF 4096
#define TRELP 196               // padded f32 per batch row (4 mod 32 banks)

__device__ __forceinline__ float b2f(bf16 x) { return __bfloat162float(x); }
__device__ __forceinline__ bf16  f2b(float x) { return __float2bfloat16(x); }

// PARENTS = [-1,0,1,2,0,4,5,0,7,8,0,10,11,0,13,14]
__device__ __forceinline__ int parent_of(int j) {
    return (j == 0) ? -1 : (((j - 1) % 3 == 0) ? 0 : j - 1);
}

template <typename T> __device__ __forceinline__ float ldv(const void* p, size_t i);
template <> __device__ __forceinline__ float ldv<float>(const void* p, size_t i) {
    return ((const float*)p)[i];
}
template <> __device__ __forceinline__ float ldv<bf16>(const void* p, size_t i) {
    return b2f(((const bf16*)p)[i]);
}

template <typename T> __device__ __forceinline__ void stv(void* p, size_t i, float v);
template <> __device__ __forceinline__ void stv<float>(void* p, size_t i, float v) {
    ((float*)p)[i] = v;
}
template <> __device__ __forceinline__ void stv<bf16>(void* p, size_t i, float v) {
    ((bf16*)p)[i] = f2b(v);
}

__device__ __forceinline__ u16 bf_bits(float x) {
    union { bf16 h; u16 u; } cvt;
    cvt.h = f2b(x);
    return cvt.u;
}
__device__ __forceinline__ float bflo(u32 u) {
    union { u32 i; float f; } t; t.i = u << 16; return t.f;
}
__device__ __forceinline__ float bfhi(u32 u) {
    union { u32 i; float f; } t; t.i = u & 0xffff0000u; return t.f;
}

// ---------------------------------------------------------------------------
// Kernel 0: dtype detector. flag=1 -> fp32.
// ---------------------------------------------------------------------------
__global__ void detect_dtype(const u16* __restrict__ betas_u, int* __restrict__ flag) {
    __shared__ int s_cnt[256];
    int tid = threadIdx.x;
    int cnt = 0;
    for (int i = tid; i < BATCH * NSHAPE; i += 256) {
        int e = (betas_u[i] >> 7) & 0xFF;
        cnt += (e >= 134) ? 1 : 0;
    }
    s_cnt[tid] = cnt;
    __syncthreads();
    for (int s = 128; s > 0; s >>= 1) {
        if (tid < s) s_cnt[tid] += s_cnt[tid + s];
        __syncthreads();
    }
    if (tid == 0) *flag = (s_cnt[0] > 1000) ? 1 : 0;
}

// ---------------------------------------------------------------------------
// Kernel A: fold J_regressor into v_template and shapedirs.
// ---------------------------------------------------------------------------
template <typename T>
__device__ void precompute_body(const void* Jreg, const void* v_template,
                                const void* shapedirs, float* jt, float* jsd) {
    int idx = blockIdx.x * blockDim.x + threadIdx.x;
    if (idx >= 48 + 480) return;
    if (idx < 48) {
        int j = idx / 3, k = idx % 3;
        float acc = 0.f;
        for (int v = 0; v < NVERT; ++v)
            acc += ldv<T>(Jreg, j * NVERT + v) * ldv<T>(v_template, v * 3 + k);
        jt[idx] = acc;
    } else {
        int o = idx - 48;
        int jk = o / NSHAPE, l = o % NSHAPE;
        int j = jk / 3, k = jk % 3;
        float acc = 0.f;
        for (int v = 0; v < NVERT; ++v)
            acc += ldv<T>(Jreg, j * NVERT + v) * ldv<T>(shapedirs, (v * 3 + k) * NSHAPE + l);
        jsd[o] = acc;
    }
}

__global__ void precompute_kernel(const void* Jreg, const void* v_template,
                                  const void* shapedirs, const int* __restrict__ flag,
                                  float* jt, float* jsd) {
    if (*flag) precompute_body<float>(Jreg, v_template, shapedirs, jt, jsd);
    else       precompute_body<bf16 >(Jreg, v_template, shapedirs, jt, jsd);
}

// ---------------------------------------------------------------------------
// Kernel A2: table builder.
// fp32 mode: transposed layout pdT[c][r][4] (float) for the vector path.
// bf16 mode: MFMA B-fragment layout. For tile t (16 cols), K-step ks (K=32),
// lane l, elem i: element = Bsrc[k = ks*32 + (l>>4)*8 + i][col = t*16+(l&15)]
// where Bsrc rows: 0..134 posedirs, 135..144 shapedirsT, 145 v_template.
// ---------------------------------------------------------------------------
__device__ void transpose_f32(const float* pd, float* pdT) {
    int idx = blockIdx.x * blockDim.x + threadIdx.x;
    if (idx >= PDT_ELEMS) return;
    int j = idx & 3;
    int rc = idx >> 2;
    int r = rc % PD_COLS;
    int c = rc / PD_COLS;
    int p = c * 4 + j;
    pdT[idx] = (p < NPF) ? pd[(size_t)p * PD_COLS + r] : 0.f;
}

__device__ void transpose_mfma(const u16* pdu, const u16* sdu, const u16* vtu,
                               u16* out) {
    int idx = blockIdx.x * blockDim.x + threadIdx.x;
    if (idx >= MT_ELEMS) return;
    int i  = idx & 7;
    int l  = (idx >> 3) & 63;
    int u  = idx >> 9;             // t*5 + ks
    int ks = u % 5, t = u / 5;
    int k   = ks * 32 + ((l >> 4) << 3) + i;
    int col = t * 16 + (l & 15);
    u16 bits = 0;
    if (col < PD_COLS) {
        if (k < NPF)                     bits = pdu[(size_t)k * PD_COLS + col];
        else if (k < NPF + NSHAPE)       bits = sdu[(size_t)col * NSHAPE + (k - NPF)];
        else if (k == NPF + NSHAPE)      bits = vtu[col];
    }
    out[idx] = bits;
}

__global__ void transpose_kernel(const void* pd, const void* sd, const void* vt,
                                 const int* __restrict__ flag, void* pdT) {
    if (*flag) transpose_f32((const float*)pd, (float*)pdT);
    else       transpose_mfma((const u16*)pd, (const u16*)sd, (const u16*)vt,
                              (u16*)pdT);
}

// ---------------------------------------------------------------------------
// Kernel B shared memory.
// ---------------------------------------------------------------------------
struct __align__(16) SmemB {
    union {
        float pff[16][144];        // fp32 vector path pose features
        u16   pfA[32][168];        // bf16 MFMA A rows: pf|beta|1|0 pad
    } pf;                          // 10752 B
    float trel[BB * TRELP];        // tm then rel, stride 196 (2-way banks) 25088 B
    union {
        float joints[BB][NJOINT][3];   // stage-1 only                6144 B
        float ldsC[NWV][16][52];       // bf16 per-wave C / out pack 26624 B
        float ob[NWV][4][192];         // fp32 vector output staging 24576 B
    } c;                           // 26624 B
    float beta[BB][NSHAPE];        // 1280 B
    float transl[BB][3];           //  384 B
    float hp[BB][NPCA];            //  768 B
};                                 // ~64.9 KB -> 2 blocks/CU, 16 waves/CU

// ---------------------------------------------------------------------------
// Stage 1: 16 batches (b0s..b0s+15) -> LDS rows ro..ro+15. 4 internal syncs.
// Threads >= 256 only participate in barriers.
// ---------------------------------------------------------------------------
template <typename T>
__device__ void stage1(const void* betas, const void* orient,
                       const void* hand_pose, const void* transl,
                       const void* hc, const void* pose_mean,
                       const float* __restrict__ jt, const float* __restrict__ jsd,
                       int b0s, int ro, void* out_base, SmemB& s) {
    const int tid = threadIdx.x;
    const bool act = (tid < 256);

    // stage 0: per-batch small inputs
    if (act) {
        if (tid < 160) {
            int q = tid / NSHAPE, l = tid % NSHAPE;
            s.beta[ro + q][l] = ldv<T>(betas, (size_t)(b0s + q) * NSHAPE + l);
        } else if (tid < 208) {
            int o = tid - 160;
            int q = o / 3, k = o % 3;
            s.transl[ro + q][k] = ldv<T>(transl, (size_t)(b0s + q) * 3 + k);
        } else {
            int o = tid - 208;
            #pragma unroll
            for (int rep = 0; rep < 2; ++rep) {
                int oo = o + rep * 48;
                int q = oo / NPCA, c = oo % NPCA;
                s.hp[ro + q][c] = ldv<T>(hand_pose, (size_t)(b0s + q) * NPCA + c);
            }
        }
    }
    __syncthreads();

    const int bb = (tid >> 4) & 15;
    const int j  = tid & 15;
    const int rb = ro + bb;
    float R[9];
    float jx[3];
    if (act) {
        float p0, p1, p2;
        if (j == 0) {
            const int b = b0s + bb;
            p0 = ldv<T>(orient, (size_t)b * 3 + 0) + ldv<T>(pose_mean, 0);
            p1 = ldv<T>(orient, (size_t)b * 3 + 1) + ldv<T>(pose_mean, 1);
            p2 = ldv<T>(orient, (size_t)b * 3 + 2) + ldv<T>(pose_mean, 2);
        } else {
            int base = 3 * (j - 1);
            p0 = ldv<T>(pose_mean, 3 * j + 0);
            p1 = ldv<T>(pose_mean, 3 * j + 1);
            p2 = ldv<T>(pose_mean, 3 * j + 2);
            #pragma unroll
            for (int c = 0; c < NPCA; ++c) {
                float hpv = s.hp[rb][c];
                p0 += hpv * ldv<T>(hc, c * 45 + base + 0);
                p1 += hpv * ldv<T>(hc, c * 45 + base + 1);
                p2 += hpv * ldv<T>(hc, c * 45 + base + 2);
            }
        }

        float r0 = p0 + 1e-8f, r1 = p1 + 1e-8f, r2 = p2 + 1e-8f;
        float angle = sqrtf(r0 * r0 + r1 * r1 + r2 * r2);
        float inv = 1.f / angle;
        float ax = p0 * inv, ay = p1 * inv, az = p2 * inv;
        float sn = sinf(angle);
        float cc1 = 1.f - cosf(angle);
        R[0] = 1.f + cc1 * (-az * az - ay * ay);
        R[1] = -sn * az + cc1 * ax * ay;
        R[2] =  sn * ay + cc1 * ax * az;
        R[3] =  sn * az + cc1 * ax * ay;
        R[4] = 1.f + cc1 * (-az * az - ax * ax);
        R[5] = -sn * ax + cc1 * ay * az;
        R[6] = -sn * ay + cc1 * ax * az;
        R[7] =  sn * ax + cc1 * ay * az;
        R[8] = 1.f + cc1 * (-ax * ax - ay * ay);

        #pragma unroll
        for (int k = 0; k < 3; ++k) {
            float acc = jt[j * 3 + k];
            #pragma unroll
            for (int l = 0; l < NSHAPE; ++l)
                acc += jsd[(j * 3 + k) * NSHAPE + l] * s.beta[rb][l];
            jx[k] = acc;
            s.c.joints[rb][j][k] = acc;
        }
    }
    __syncthreads();

    // local transform [R | joint - parent_joint] into trel
    if (act) {
        int par = parent_of(j);
        float* tm = &s.trel[(size_t)rb * TRELP + j * 12];
        #pragma unroll
        for (int m = 0; m < 3; ++m) {
            float t = jx[m] - (j > 0 ? s.c.joints[rb][par][m] : 0.f);
            tm[m * 4 + 0] = R[m * 3 + 0];
            tm[m * 4 + 1] = R[m * 3 + 1];
            tm[m * 4 + 2] = R[m * 3 + 2];
            tm[m * 4 + 3] = t;
        }
    }
    __syncthreads();

    // chain walk
    float G[12];
    if (act) {
        int stack[3];
        int depth = 0;
        int i = j;
        while (i != 0 && depth < 3) { stack[depth++] = i; i = parent_of(i); }
        const float* base = &s.trel[(size_t)rb * TRELP];
        #pragma unroll
        for (int t = 0; t < 12; ++t) G[t] = base[t];
        for (int d = depth - 1; d >= 0; --d) {
            const float* Tc = base + stack[d] * 12;
            float Gn[12];
            #pragma unroll
            for (int m = 0; m < 3; ++m) {
                #pragma unroll
                for (int n = 0; n < 4; ++n) {
                    float acc = G[m * 4 + 0] * Tc[0 * 4 + n] +
                                G[m * 4 + 1] * Tc[1 * 4 + n] +
                                G[m * 4 + 2] * Tc[2 * 4 + n];
                    if (n == 3) acc += G[m * 4 + 3];
                    Gn[m * 4 + n] = acc;
                }
            }
            #pragma unroll
            for (int t = 0; t < 12; ++t) G[t] = Gn[t];
        }
    }
    __syncthreads();    // all chain reads done; now overwrite with rel

    if (act) {
        // posed joints out (+ transl)
        size_t jo = VERT_ELEMS + ((size_t)(b0s + bb) * NJOINT + j) * 3;
        stv<T>(out_base, jo + 0, G[0 * 4 + 3] + s.transl[rb][0]);
        stv<T>(out_base, jo + 1, G[1 * 4 + 3] + s.transl[rb][1]);
        stv<T>(out_base, jo + 2, G[2 * 4 + 3] + s.transl[rb][2]);

        float* rl = &s.trel[(size_t)rb * TRELP + j * 12];
        #pragma unroll
        for (int m = 0; m < 3; ++m) {
            float rbv = G[m * 4 + 3] -
                        (G[m * 4 + 0] * jx[0] + G[m * 4 + 1] * jx[1] + G[m * 4 + 2] * jx[2]);
            rl[m * 4 + 0] = G[m * 4 + 0];
            rl[m * 4 + 1] = G[m * 4 + 1];
            rl[m * 4 + 2] = G[m * 4 + 2];
            rl[m * 4 + 3] = rbv;
        }

        if constexpr (sizeof(T) == 2) {
            u16* pa = &s.pf.pfA[rb][0];
            if (j > 0) {
                u16* po = pa + (j - 1) * 9;
                po[0] = bf_bits(R[0] - 1.f); po[1] = bf_bits(R[1]);       po[2] = bf_bits(R[2]);
                po[3] = bf_bits(R[3]);       po[4] = bf_bits(R[4] - 1.f); po[5] = bf_bits(R[5]);
                po[6] = bf_bits(R[6]);       po[7] = bf_bits(R[7]);       po[8] = bf_bits(R[8] - 1.f);
            } else {
                #pragma unroll
                for (int l2 = 0; l2 < NSHAPE; ++l2)
                    pa[NPF + l2] = bf_bits(s.beta[rb][l2]);
                pa[NPF + NSHAPE] = 0x3F80;  // 1.0 bf16
                #pragma unroll
                for (int z = NPF + NSHAPE + 1; z < 168; ++z) pa[z] = 0;
            }
        } else {
            float* pa = s.pf.pff[bb];
            if (j > 0) {
                float* po = pa + (j - 1) * 9;
                po[0] = R[0] - 1.f; po[1] = R[1];       po[2] = R[2];
                po[3] = R[3];       po[4] = R[4] - 1.f; po[5] = R[5];
                po[6] = R[6];       po[7] = R[7];       po[8] = R[8] - 1.f;
            } else {
                #pragma unroll
                for (int z = NPF; z < 144; ++z) pa[z] = 0.f;
            }
        }
    }
    __syncthreads();
}

// ---------------------------------------------------------------------------
// bf16 MFMA stage 2 helpers.
// ---------------------------------------------------------------------------
__device__ __forceinline__ void lbs_calc(const void* lbsw, int h, int sp,
                                         SmemB& s, float (*ldsC)[52], int l,
                                         u32 out6[6]) {
    const int lb = l & 15, vg = l >> 4;
    asm volatile("s_waitcnt lgkmcnt(0)" ::: "memory");
    __builtin_amdgcn_sched_barrier(0);

    float a4[4][3];
    #pragma unroll
    for (int vv = 0; vv < 4; ++vv)
        #pragma unroll
        for (int cc = 0; cc < 3; ++cc)
            a4[vv][cc] = ldsC[lb][(vg * 4 + vv) * 3 + cc];

    uint4 wr[4][2];
    #pragma unroll
    for (int vv = 0; vv < 4; ++vv) {
        int v = sp * 16 + vg * 4 + vv;
        if (v > NVERT - 1) v = NVERT - 1;
        const uint4* wp = (const uint4*)((const u16*)lbsw + (size_t)v * NJOINT);
        wr[vv][0] = wp[0];
        wr[vv][1] = wp[1];
    }

    const float* relb = &s.trel[(size_t)(h * 16 + lb) * TRELP];
    float Tm[4][12];
    #pragma unroll
    for (int vv = 0; vv < 4; ++vv)
        #pragma unroll
        for (int q = 0; q < 12; ++q) Tm[vv][q] = 0.f;

    #pragma unroll
    for (int jj = 0; jj < NJOINT; ++jj) {
        const float4 r0 = *(const float4*)(relb + jj * 12 + 0);
        const float4 r1 = *(const float4*)(relb + jj * 12 + 4);
        const float4 r2 = *(const float4*)(relb + jj * 12 + 8);
        #pragma unroll
        for (int vv = 0; vv < 4; ++vv) {
            const uint4 wu = wr[vv][(jj >> 3) & 1];
            const int wc = (jj >> 1) & 3;
            const u32 ww = (wc == 0) ? wu.x : (wc == 1) ? wu.y : (wc == 2) ? wu.z : wu.w;
            const float wj = (jj & 1) ? bfhi(ww) : bflo(ww);
            Tm[vv][0] += wj * r0.x; Tm[vv][1]  += wj * r0.y; Tm[vv][2]  += wj * r0.z; Tm[vv][3]  += wj * r0.w;
            Tm[vv][4] += wj * r1.x; Tm[vv][5]  += wj * r1.y; Tm[vv][6]  += wj * r1.z; Tm[vv][7]  += wj * r1.w;
            Tm[vv][8] += wj * r2.x; Tm[vv][9]  += wj * r2.y; Tm[vv][10] += wj * r2.z; Tm[vv][11] += wj * r2.w;
        }
    }

    const float t0 = s.transl[h * 16 + lb][0];
    const float t1 = s.transl[h * 16 + lb][1];
    const float t2 = s.transl[h * 16 + lb][2];
    float o[4][3];
    #pragma unroll
    for (int vv = 0; vv < 4; ++vv) {
        o[vv][0] = Tm[vv][0] * a4[vv][0] + Tm[vv][1] * a4[vv][1] + Tm[vv][2]  * a4[vv][2] + Tm[vv][3]  + t0;
        o[vv][1] = Tm[vv][4] * a4[vv][0] + Tm[vv][5] * a4[vv][1] + Tm[vv][6]  * a4[vv][2] + Tm[vv][7]  + t1;
        o[vv][2] = Tm[vv][8] * a4[vv][0] + Tm[vv][9] * a4[vv][1] + Tm[vv][10] * a4[vv][2] + Tm[vv][11] + t2;
    }

    out6[0] = (u32)bf_bits(o[0][0]) | ((u32)bf_bits(o[0][1]) << 16);
    out6[1] = (u32)bf_bits(o[0][2]) | ((u32)bf_bits(o[1][0]) << 16);
    out6[2] = (u32)bf_bits(o[1][1]) | ((u32)bf_bits(o[1][2]) << 16);
    out6[3] = (u32)bf_bits(o[2][0]) | ((u32)bf_bits(o[2][1]) << 16);
    out6[4] = (u32)bf_bits(o[2][2]) | ((u32)bf_bits(o[3][0]) << 16);
    out6[5] = (u32)bf_bits(o[3][1]) | ((u32)bf_bits(o[3][2]) << 16);
}

// compute one super-tile sp for both halves; results in rh0/rh1.
__device__ __forceinline__ void super_tile(const u16* __restrict__ pdTm,
                                           const void* lbsw, int sp,
                                           const short8* afr0, const short8* afr1,
                                           SmemB& s, float (*ldsC)[52],
                                           int l, int lq, int lb,
                                           u32 rh0[6], u32 rh1[6]) {
    f32x4 acc1[3];
    #pragma unroll
    for (int tt = 0; tt < 3; ++tt) {
        const int t = sp * 3 + tt;
        f32x4 a0 = {0.f, 0.f, 0.f, 0.f};
        f32x4 a1 = {0.f, 0.f, 0.f, 0.f};
        #pragma unroll
        for (int ks = 0; ks < 5; ++ks) {
            const short8 bfr = *(const short8*)(pdTm + (((size_t)t * 5 + ks) * 64 + l) * 8);
            a0 = __builtin_amdgcn_mfma_f32_16x16x32_bf16(afr0[ks], bfr, a0, 0, 0, 0);
            a1 = __builtin_amdgcn_mfma_f32_16x16x32_bf16(afr1[ks], bfr, a1, 0, 0, 0);
        }
        #pragma unroll
        for (int r = 0; r < 4; ++r) ldsC[lq * 4 + r][tt * 16 + lb] = a0[r];
        acc1[tt] = a1;
    }
    lbs_calc(lbsw, 0, sp, s, ldsC, l, rh0);
    #pragma unroll
    for (int tt = 0; tt < 3; ++tt)
        #pragma unroll
        for (int r = 0; r < 4; ++r) ldsC[lq * 4 + r][tt * 16 + lb] = acc1[tt][r];
    lbs_calc(lbsw, 1, sp, s, ldsC, l, rh1);
}

__device__ void mfma_stage2(const u16* __restrict__ pdTm, const void* lbsw,
                            int b0, void* out_base, SmemB& s) {
    const int tid = threadIdx.x;
    const int wv = tid >> 6, l = tid & 63;
    const int lb = l & 15, lq = l >> 4;
    const int vg = l >> 4;
    float (*ldsC)[52] = s.c.ldsC[wv];

    for (int p = wv; p < NPAIR; p += NWV) {
        short8 afr0[5], afr1[5];
        #pragma unroll
        for (int ks = 0; ks < 5; ++ks) {
            afr0[ks] = *(const short8*)&s.pf.pfA[lb][ks * 32 + lq * 8];
            afr1[ks] = *(const short8*)&s.pf.pfA[16 + lb][ks * 32 + lq * 8];
        }

        u32 r00[6], r01[6], r10[6], r11[6];
        #pragma unroll
        for (int k = 0; k < 6; ++k) { r10[k] = 0u; r11[k] = 0u; }

        super_tile(pdTm, lbsw, 2 * p, afr0, afr1, s, ldsC, l, lq, lb, r00, r01);
        if (p < NPAIR - 1)   // last pair is a singleton (sp=48)
            super_tile(pdTm, lbsw, 2 * p + 1, afr0, afr1, s, ldsC, l, lq, lb, r10, r11);

        // pack both sps + write: 48 u32 (192 B) per batch row.
        const int nw = (p == NPAIR - 1) ? 15 : 48;   // valid u32 per row
        #pragma unroll
        for (int h = 0; h < 2; ++h) {
            const u32* rA = (h == 0) ? r00 : r01;
            const u32* rB = (h == 0) ? r10 : r11;
            asm volatile("s_waitcnt lgkmcnt(0)" ::: "memory");
            __builtin_amdgcn_sched_barrier(0);
            u32* row = (u32*)&ldsC[lb][0];
            #pragma unroll
            for (int k = 0; k < 6; ++k) {
                row[vg * 6 + k]      = rA[k];
                row[24 + vg * 6 + k] = rB[k];
            }
            asm volatile("s_waitcnt lgkmcnt(0)" ::: "memory");
            __builtin_amdgcn_sched_barrier(0);
            #pragma unroll
            for (int it = 0; it < 12; ++it) {
                const int i = it * 64 + l;
                const int bb2 = i / 48, c2 = i - bb2 * 48;
                if (c2 < nw) {
                    const u32 val = ((const u32*)&ldsC[bb2][0])[c2];
                    *(u32*)((char*)out_base + (size_t)(b0 + h * 16 + bb2) * (NVERT * 3 * 2)
                            + (size_t)p * 192 + (size_t)c2 * 4) = val;
                }
            }
        }
    }
}

// ---------------------------------------------------------------------------
// Vector stage 2 (fp32 TRP = transposed table; generic otherwise).
// Operates on LDS rows 0..15 / batches b0s..b0s+15. 512 threads, 8 waves.
// ---------------------------------------------------------------------------
template <typename T, bool TRP>
__device__ void vector_stage2(const void* v_template, const void* shapedirs,
                              const void* posedirs, const void* lbsw,
                              const void* __restrict__ pdTv,
                              int b0s, void* out_base, SmemB& s) {
    const int tid = threadIdx.x;
    const int wv = tid >> 6;       // 0..7
    const int ln = tid & 63;

    for (int iter = 0; iter < 2; ++iter) {
        const int vbase = iter * 512 + wv * 64;
        if (vbase >= NVERT) break;
        const int nv = (NVERT - vbase < 64) ? (NVERT - vbase) : 64;
        const int v  = vbase + ln;
        const int vc = (v < NVERT) ? v : (NVERT - 1);
        const int v3 = vc * 3;

        float a[16][3];
        {
            const float q0 = ldv<T>(v_template, v3 + 0);
            const float q1 = ldv<T>(v_template, v3 + 1);
            const float q2 = ldv<T>(v_template, v3 + 2);
            #pragma unroll
            for (int q = 0; q < 16; ++q) { a[q][0] = q0; a[q][1] = q1; a[q][2] = q2; }
        }

        #pragma unroll
        for (int l = 0; l < NSHAPE; ++l) {
            const float sd0 = ldv<T>(shapedirs, (size_t)vc * 30 + 0 * NSHAPE + l);
            const float sd1 = ldv<T>(shapedirs, (size_t)vc * 30 + 1 * NSHAPE + l);
            const float sd2 = ldv<T>(shapedirs, (size_t)vc * 30 + 2 * NSHAPE + l);
            #pragma unroll
            for (int q = 0; q < 16; ++q) {
                const float be = s.beta[q][l];
                a[q][0] += be * sd0;
                a[q][1] += be * sd1;
                a[q][2] += be * sd2;
            }
        }

        auto fma_chunk = [&](float4 px, float4 py, float4 pz, int c) {
            #pragma unroll
            for (int q = 0; q < 16; ++q) {
                const float4 f = *(const float4*)&s.pf.pff[q][c * 4];
                a[q][0] += f.x * px.x + f.y * px.y + f.z * px.z + f.w * px.w;
                a[q][1] += f.x * py.x + f.y * py.y + f.z * py.z + f.w * py.w;
                a[q][2] += f.x * pz.x + f.y * pz.y + f.z * pz.z + f.w * pz.w;
            }
        };

        if constexpr (TRP && sizeof(T) == 4) {
            const float4* __restrict__ pdT4 = (const float4*)pdTv;
            float4 ax = pdT4[(size_t)0 * PD_COLS + v3 + 0];
            float4 ay = pdT4[(size_t)0 * PD_COLS + v3 + 1];
            float4 az = pdT4[(size_t)0 * PD_COLS + v3 + 2];
            float4 bx = pdT4[(size_t)1 * PD_COLS + v3 + 0];
            float4 by = pdT4[(size_t)1 * PD_COLS + v3 + 1];
            float4 bz = pdT4[(size_t)1 * PD_COLS + v3 + 2];
            #pragma unroll 1
            for (int c = 0; c < NCHUNK; c += 2) {
                const size_t n2 = (size_t)(c + 2) * PD_COLS + v3;
                const size_t n3 = (size_t)(c + 3) * PD_COLS + v3;
                float4 cx = pdT4[n2 + 0], cy = pdT4[n2 + 1], cz = pdT4[n2 + 2];
                float4 dx = pdT4[n3 + 0], dy = pdT4[n3 + 1], dz = pdT4[n3 + 2];
                fma_chunk(ax, ay, az, c);
                fma_chunk(bx, by, bz, c + 1);
                ax = cx; ay = cy; az = cz;
                bx = dx; by = dy; bz = dz;
            }
        } else {
            #pragma unroll 1
            for (int c = 0; c < NCHUNK; ++c) {
                const int p = c * 4;
                float pdx[4], pdy[4], pdz[4];
                #pragma unroll
                for (int qq = 0; qq < 3; ++qq) {
                    pdx[qq] = ldv<T>(posedirs, (size_t)(p + qq) * PD_COLS + v3 + 0);
                    pdy[qq] = ldv<T>(posedirs, (size_t)(p + qq) * PD_COLS + v3 + 1);
                    pdz[qq] = ldv<T>(posedirs, (size_t)(p + qq) * PD_COLS + v3 + 2);
                }
                if (p + 3 < NPF) {
                    pdx[3] = ldv<T>(posedirs, (size_t)(p + 3) * PD_COLS + v3 + 0);
                    pdy[3] = ldv<T>(posedirs, (size_t)(p + 3) * PD_COLS + v3 + 1);
                    pdz[3] = ldv<T>(posedirs, (size_t)(p + 3) * PD_COLS + v3 + 2);
                } else {
                    pdx[3] = 0.f; pdy[3] = 0.f; pdz[3] = 0.f;
                }
                fma_chunk(make_float4(pdx[0], pdx[1], pdx[2], pdx[3]),
                          make_float4(pdy[0], pdy[1], pdy[2], pdy[3]),
                          make_float4(pdz[0], pdz[1], pdz[2], pdz[3]), c);
            }
        }

        float w[NJOINT];
        if constexpr (sizeof(T) == 4) {
            const float4* wl = (const float4*)((const float*)lbsw + (size_t)vc * NJOINT);
            #pragma unroll
            for (int g = 0; g < 4; ++g) {
                const float4 t = wl[g];
                w[g * 4 + 0] = t.x; w[g * 4 + 1] = t.y;
                w[g * 4 + 2] = t.z; w[g * 4 + 3] = t.w;
            }
        } else {
            const uint4* wl = (const uint4*)((const u16*)lbsw + (size_t)vc * NJOINT);
            const uint4 w0 = wl[0], w1 = wl[1];
            w[0]  = bflo(w0.x); w[1]  = bfhi(w0.x);
            w[2]  = bflo(w0.y); w[3]  = bfhi(w0.y);
            w[4]  = bflo(w0.z); w[5]  = bfhi(w0.z);
            w[6]  = bflo(w0.w); w[7]  = bfhi(w0.w);
            w[8]  = bflo(w1.x); w[9]  = bfhi(w1.x);
            w[10] = bflo(w1.y); w[11] = bfhi(w1.y);
            w[12] = bflo(w1.z); w[13] = bfhi(w1.z);
            w[14] = bflo(w1.w); w[15] = bfhi(w1.w);
        }

        const int n32 = (nv * 3 * (int)sizeof(T)) >> 2;
        #pragma unroll 1
        for (int g = 0; g < 4; ++g) {
            #pragma unroll
            for (int qq = 0; qq < 4; ++qq) {
                const int q = g * 4 + qq;
                float Tm[12];
                #pragma unroll
                for (int t = 0; t < 12; ++t) Tm[t] = 0.f;
                #pragma unroll
                for (int jj = 0; jj < NJOINT; ++jj) {
                    const float* rl = &s.trel[(size_t)q * TRELP + jj * 12];
                    const float4 r0 = *(const float4*)(rl + 0);
                    const float4 r1 = *(const float4*)(rl + 4);
                    const float4 r2 = *(const float4*)(rl + 8);
                    const float wj = w[jj];
                    Tm[0] += wj * r0.x; Tm[1]  += wj * r0.y; Tm[2]  += wj * r0.z; Tm[3]  += wj * r0.w;
                    Tm[4] += wj * r1.x; Tm[5]  += wj * r1.y; Tm[6]  += wj * r1.z; Tm[7]  += wj * r1.w;
                    Tm[8] += wj * r2.x; Tm[9]  += wj * r2.y; Tm[10] += wj * r2.z; Tm[11] += wj * r2.w;
                }
                const float o0 = Tm[0] * a[q][0] + Tm[1] * a[q][1] + Tm[2]  * a[q][2] + Tm[3]  + s.transl[q][0];
                const float o1 = Tm[4] * a[q][0] + Tm[5] * a[q][1] + Tm[6]  * a[q][2] + Tm[7]  + s.transl[q][1];
                const float o2 = Tm[8] * a[q][0] + Tm[9] * a[q][1] + Tm[10] * a[q][2] + Tm[11] + s.transl[q][2];
                if constexpr (sizeof(T) == 4) {
                    float* ob = &s.c.ob[wv][qq][0];
                    ob[ln * 3 + 0] = o0;
                    ob[ln * 3 + 1] = o1;
                    ob[ln * 3 + 2] = o2;
                } else {
                    u16* ob = (u16*)&s.c.ob[wv][qq][0];
                    ob[ln * 3 + 0] = bf_bits(o0);
                    ob[ln * 3 + 1] = bf_bits(o1);
                    ob[ln * 3 + 2] = bf_bits(o2);
                }
            }
            #pragma unroll
            for (int qq = 0; qq < 4; ++qq) {
                const int q = g * 4 + qq;
                const u32* src = (const u32*)&s.c.ob[wv][qq][0];
                u32* dst = (u32*)((char*)out_base +
                                  ((size_t)(b0s + q) * NVERT + vbase) * 3 * sizeof(T));
                #pragma unroll
                for (int k = 0; k < 3; ++k) {
                    const int idx = k * 64 + ln;
                    if (idx < n32) dst[idx] = src[idx];
                }
            }
        }
    }
}

// ---------------------------------------------------------------------------
template <bool TRP>
__global__ __launch_bounds__(NTHR, 4) void mano_fused(
    const void* betas, const void* orient, const void* hand_pose,
    const void* transl, const void* hc, const void* pose_mean,
    const void* v_template, const void* shapedirs, const void* posedirs,
    const void* lbsw, const int* __restrict__ flag,
    const float* __restrict__ jt, const float* __restrict__ jsd,
    const void* __restrict__ pdT,
    void* out_base) {
    __shared__ SmemB s;
    const int b0 = blockIdx.x * BB;

    if (*flag) {
        #pragma unroll 1
        for (int rep = 0; rep < 2; ++rep) {
            stage1<float>(betas, orient, hand_pose, transl, hc, pose_mean,
                          jt, jsd, b0 + rep * 16, 0, out_base, s);
            vector_stage2<float, TRP>(v_template, shapedirs, posedirs, lbsw,
                                      pdT, b0 + rep * 16, out_base, s);
            __syncthreads();
        }
    } else {
        if constexpr (TRP) {
            stage1<bf16>(betas, orient, hand_pose, transl, hc, pose_mean,
                         jt, jsd, b0, 0, out_base, s);
            stage1<bf16>(betas, orient, hand_pose, transl, hc, pose_mean,
                         jt, jsd, b0 + 16, 16, out_base, s);
            mfma_stage2((const u16*)pdT, lbsw, b0, out_base, s);
        } else {
            #pragma unroll 1
            for (int rep = 0; rep < 2; ++rep) {
                stage1<bf16>(betas, orient, hand_pose, transl, hc, pose_mean,
                             jt, jsd, b0 + rep * 16, 0, out_base, s);
                vector_stage2<bf16, false>(v_template, shapedirs, posedirs, lbsw,
                                           pdT, b0 + rep * 16, out_base, s);
                __syncthreads();
            }
        }
    }
}

// ---------------------------------------------------------------------------
extern "C" void kernel_launch(void* const* d_in, const int* in_sizes, int n_in,
                              void* d_out, int out_size, void* d_ws, size_t ws_size,
                              hipStream_t stream) {
    const void* betas      = d_in[0];
    const void* orient     = d_in[1];
    const void* hand_pose  = d_in[2];
    const void* transl     = d_in[3];
    const void* hc         = d_in[4];
    const void* pose_mean  = d_in[5];
    const void* v_template = d_in[6];
    const void* shapedirs  = d_in[7];
    const void* posedirs   = d_in[8];
    const void* Jreg       = d_in[9];
    const void* lbsw       = d_in[10];
    // d_in[11] (parents) intentionally ignored — tree is hardcoded.

    int*   flag = (int*)d_ws;
    float* jt   = (float*)d_ws + 16;
    float* jsd  = (float*)d_ws + 64;
    void*  pdT  = (void*)((char*)d_ws + PDT_BYTE_OFF);

    // worst case (fp32 table): 36 chunks * 2334 * 4 elems * 4 B
    const bool trp = ws_size >= (size_t)PDT_BYTE_OFF + (size_t)PDT_ELEMS * 4;

    hipLaunchKernelGGL(detect_dtype, dim3(1), dim3(256), 0, stream,
                       (const u16*)betas, flag);
    hipLaunchKernelGGL(precompute_kernel, dim3(3), dim3(192), 0, stream,
                       Jreg, v_template, shapedirs, flag, jt, jsd);
    if (trp) {
        hipLaunchKernelGGL(transpose_kernel, dim3((MT_ELEMS + 255) / 256), dim3(256),
                           0, stream, posedirs, shapedirs, v_template, flag, pdT);
        hipLaunchKernelGGL(mano_fused<true>, dim3(NBLK), dim3(NTHR), 0, stream,
                           betas, orient, hand_pose, transl, hc, pose_mean,
                           v_template, shapedirs, posedirs, lbsw, flag, jt, jsd,
                           pdT, d_out);
    } else {
        hipLaunchKernelGGL(mano_fused<false>, dim3(NBLK), dim3(NTHR), 0, stream,
                           betas, orient, hand_pose, transl, hc, pose_mean,
                           v_template, shapedirs, posedirs, lbsw, flag, jt, jsd,
                           pdT, d_out);
    }
    (void)in_sizes; (void)n_in; (void)out_size; (void)ws_size;
}